// Round 3
// baseline (481.816 us; speedup 1.0000x reference)
//
#include <hip/hip_runtime.h>

typedef unsigned short u16;
typedef __attribute__((ext_vector_type(8))) short bf16x8;
typedef __attribute__((ext_vector_type(4))) float f32x4;

#define MFMA16(A,B,C) __builtin_amdgcn_mfma_f32_16x16x32_bf16(A,B,C,0,0,0)

#define B_ 4
#define C_ 256
#define N_ 2304
#define HEADS_ 8
#define DH_ 64
#define INNER_ 512

__device__ __forceinline__ u16 f2bf(float f) {
    union { float f; unsigned int u; } v; v.f = f;
    unsigned int r = v.u + 0x7fffu + ((v.u >> 16) & 1u);
    return (u16)(r >> 16);
}

// ---------------- Kernel C: fp32 -> bf16 convert (weights) ----------------
__global__ __launch_bounds__(256) void k_cvt(const float* __restrict__ src,
                                             u16* __restrict__ dst, int n4) {
    int i = blockIdx.x * 256 + threadIdx.x;
    if (i < n4) {
        float4 v = ((const float4*)src)[i];
        ushort4 o;
        o.x = f2bf(v.x); o.y = f2bf(v.y); o.z = f2bf(v.z); o.w = f2bf(v.w);
        ((ushort4*)dst)[i] = o;
    }
}

// ---------------- Kernel 0: transpose x [B][C][N] (f32) -> xT [B][N][C] (bf16) ----------------
__global__ __launch_bounds__(256) void k_transpose(const float* __restrict__ x,
                                                   u16* __restrict__ xT) {
    __shared__ float tile[64][65];
    int b = blockIdx.z;
    int n0 = blockIdx.x * 64, c0 = blockIdx.y * 64;
    const float* xb = x + (size_t)b * C_ * N_;
    u16* xTb = xT + (size_t)b * N_ * C_;
    int t = threadIdx.x;
    int r = t >> 4;          // 0..15
    int q4 = (t & 15) * 4;   // 0,4,..,60
#pragma unroll
    for (int pass = 0; pass < 4; ++pass) {
        int c = r + pass * 16;
        float4 v = *(const float4*)(xb + (size_t)(c0 + c) * N_ + n0 + q4);
        tile[c][q4+0] = v.x; tile[c][q4+1] = v.y; tile[c][q4+2] = v.z; tile[c][q4+3] = v.w;
    }
    __syncthreads();
#pragma unroll
    for (int pass = 0; pass < 4; ++pass) {
        int n = r + pass * 16;
        ushort4 o;
        o.x = f2bf(tile[q4+0][n]); o.y = f2bf(tile[q4+1][n]);
        o.z = f2bf(tile[q4+2][n]); o.w = f2bf(tile[q4+3][n]);
        *(ushort4*)(xTb + (size_t)(n0 + n) * C_ + c0 + q4) = o;
    }
}

// ---------------- Kernel 1: QKV GEMM + l2norm(q,k) + layout ----------------
// out[o][n] = sum_c w_qkv[o][c] * xT[n][c];  o = which*512 + h*64 + d
// Q,K stored [b][h][n][d] (l2-normalized over d); V stored transposed [b][h][d][n].
__global__ __launch_bounds__(256) void k_qkv(const u16* __restrict__ w_qkv,
                                             const u16* __restrict__ xT,
                                             u16* __restrict__ Qn,
                                             u16* __restrict__ Kn,
                                             u16* __restrict__ Vt) {
    int mt = blockIdx.x, nt = blockIdx.y, b = blockIdx.z;
    int wv = threadIdx.x >> 6, lane = threadIdx.x & 63;
    int col = lane & 15, quad = lane >> 4;
    int o0 = mt * 64;
    int n = nt * 64 + wv * 16 + col;
    const u16* xrow = xT + ((size_t)b * N_ + n) * C_;
    f32x4 z = {0.f, 0.f, 0.f, 0.f};
    f32x4 acc[4]; acc[0]=z; acc[1]=z; acc[2]=z; acc[3]=z;
#pragma unroll
    for (int ks = 0; ks < 8; ++ks) {
        bf16x8 bfrag = *(const bf16x8*)(xrow + ks*32 + quad*8);
#pragma unroll
        for (int mb = 0; mb < 4; ++mb) {
            bf16x8 afrag = *(const bf16x8*)(w_qkv + (size_t)(o0 + mb*16 + col) * C_ + ks*32 + quad*8);
            acc[mb] = MFMA16(afrag, bfrag, acc[mb]);
        }
    }
    int which = mt >> 3, h = mt & 7;
    if (which < 2) {
        float s = 0.f;
#pragma unroll
        for (int mb = 0; mb < 4; ++mb)
#pragma unroll
            for (int r = 0; r < 4; ++r) s += acc[mb][r] * acc[mb][r];
        s += __shfl_xor(s, 16);
        s += __shfl_xor(s, 32);
        float inv = 1.f / fmaxf(sqrtf(s), 1e-12f);
        u16* dst = (which == 0 ? Qn : Kn) + (((size_t)b * HEADS_ + h) * N_ + n) * DH_;
#pragma unroll
        for (int mb = 0; mb < 4; ++mb) {
            ushort4 o;
            o.x = f2bf(acc[mb][0] * inv); o.y = f2bf(acc[mb][1] * inv);
            o.z = f2bf(acc[mb][2] * inv); o.w = f2bf(acc[mb][3] * inv);
            *(ushort4*)(dst + mb*16 + quad*4) = o;
        }
    } else {
        u16* dst = Vt + ((size_t)b * HEADS_ + h) * (size_t)DH_ * N_;
#pragma unroll
        for (int mb = 0; mb < 4; ++mb)
#pragma unroll
            for (int r = 0; r < 4; ++r)
                dst[(size_t)(mb*16 + quad*4 + r) * N_ + n] = f2bf(acc[mb][r]);
    }
}

// ---------------- Kernel 2: flash attention ----------------
// Per block: (q-tile of 64, h, b). 4 waves x 16 q-rows. Online softmax.
// Output AO[b][n][h*64+d] (B-operand-ready for out-proj).
__global__ __launch_bounds__(256) void k_attn(const u16* __restrict__ Qn,
                                              const u16* __restrict__ Kn,
                                              const u16* __restrict__ Vt,
                                              u16* __restrict__ AO) {
    __shared__ __align__(16) u16 plds[4][16][72];   // stride 72*2=144B (16B-aligned rows)
    int qt = blockIdx.x, h = blockIdx.y, b = blockIdx.z;
    int wv = threadIdx.x >> 6, lane = threadIdx.x & 63;
    int col = lane & 15, quad = lane >> 4;
    size_t head = (size_t)b * HEADS_ + h;
    const u16* Qh = Qn + head * (size_t)N_ * DH_;
    const u16* Kh = Kn + head * (size_t)N_ * DH_;
    const u16* Vh = Vt + head * (size_t)DH_ * N_;
    int q0 = qt * 64 + wv * 16;
    bf16x8 qf0 = *(const bf16x8*)(Qh + (size_t)(q0 + col) * DH_ + quad*8);
    bf16x8 qf1 = *(const bf16x8*)(Qh + (size_t)(q0 + col) * DH_ + 32 + quad*8);
    f32x4 z = {0.f, 0.f, 0.f, 0.f};
    f32x4 O[4]; O[0]=z; O[1]=z; O[2]=z; O[3]=z;
    float m_i[4], l_i[4];
#pragma unroll
    for (int r = 0; r < 4; ++r) { m_i[r] = -1e30f; l_i[r] = 0.f; }

    for (int kt = 0; kt < N_/64; ++kt) {
        // S = (Q K^T) * 10
        f32x4 S[4];
#pragma unroll
        for (int nb = 0; nb < 4; ++nb) {
            const u16* krow = Kh + (size_t)(kt*64 + nb*16 + col) * DH_;
            f32x4 a = z;
            a = MFMA16(qf0, *(const bf16x8*)(krow + quad*8), a);
            a = MFMA16(qf1, *(const bf16x8*)(krow + 32 + quad*8), a);
            S[nb] = a * 10.f;
        }
        // online softmax: row max / exp / row sum (rows live across 16 lanes of a quad)
        float mnew[4], rs[4], alpha[4];
#pragma unroll
        for (int r = 0; r < 4; ++r) {
            float mx = fmaxf(fmaxf(S[0][r], S[1][r]), fmaxf(S[2][r], S[3][r]));
#pragma unroll
            for (int msk = 1; msk <= 8; msk <<= 1) mx = fmaxf(mx, __shfl_xor(mx, msk));
            mnew[r] = fmaxf(m_i[r], mx);
            alpha[r] = __expf(m_i[r] - mnew[r]);
        }
#pragma unroll
        for (int r = 0; r < 4; ++r) {
            float srow = 0.f;
#pragma unroll
            for (int nb = 0; nb < 4; ++nb) {
                float p = __expf(S[nb][r] - mnew[r]);
                S[nb][r] = p;
                srow += p;
            }
#pragma unroll
            for (int msk = 1; msk <= 8; msk <<= 1) srow += __shfl_xor(srow, msk);
            rs[r] = srow;
        }
#pragma unroll
        for (int r = 0; r < 4; ++r) { l_i[r] = l_i[r] * alpha[r] + rs[r]; m_i[r] = mnew[r]; }
#pragma unroll
        for (int nb = 0; nb < 4; ++nb)
#pragma unroll
            for (int r = 0; r < 4; ++r) O[nb][r] *= alpha[r];
        // P (C-layout) -> LDS -> A-layout (wave-private region; DS pipe is in-order per wave)
#pragma unroll
        for (int nb = 0; nb < 4; ++nb)
#pragma unroll
            for (int r = 0; r < 4; ++r)
                plds[wv][quad*4 + r][nb*16 + col] = f2bf(S[nb][r]);
        __asm__ volatile("" ::: "memory");
        // O += P V
#pragma unroll
        for (int ks = 0; ks < 2; ++ks) {
            bf16x8 pf = *(const bf16x8*)(&plds[wv][col][ks*32 + quad*8]);
#pragma unroll
            for (int nb = 0; nb < 4; ++nb) {
                const u16* vrow = Vh + (size_t)(nb*16 + col) * N_ + kt*64 + ks*32 + quad*8;
                O[nb] = MFMA16(pf, *(const bf16x8*)(vrow), O[nb]);
            }
        }
        __asm__ volatile("" ::: "memory");
    }
#pragma unroll
    for (int r = 0; r < 4; ++r) l_i[r] = 1.f / l_i[r];
    u16* dst = AO + ((size_t)b * N_ + q0) * INNER_ + h * DH_;
#pragma unroll
    for (int nb = 0; nb < 4; ++nb)
#pragma unroll
        for (int r = 0; r < 4; ++r)
            dst[(size_t)(quad*4 + r) * INNER_ + nb*16 + col] = f2bf(O[nb][r] * l_i[r]);
}

// ---------------- Kernel 3: output projection + bias (fp32 output) ----------------
// out[b][o][n] = sum_i w_out[o][i] * AO[b][n][i] + b_out[o]
__global__ __launch_bounds__(256) void k_proj(const u16* __restrict__ w_out,
                                              const float* __restrict__ b_out,
                                              const u16* __restrict__ AO,
                                              float* __restrict__ out) {
    int mt = blockIdx.x, nt = blockIdx.y, b = blockIdx.z;
    int wv = threadIdx.x >> 6, lane = threadIdx.x & 63;
    int col = lane & 15, quad = lane >> 4;
    int o0 = mt * 64 + wv * 16;
    f32x4 z = {0.f, 0.f, 0.f, 0.f};
    f32x4 acc[4]; acc[0]=z; acc[1]=z; acc[2]=z; acc[3]=z;
    const u16* arow_base = AO + ((size_t)b * N_ + nt*64) * INNER_;
#pragma unroll
    for (int ks = 0; ks < 16; ++ks) {
        bf16x8 af = *(const bf16x8*)(w_out + (size_t)(o0 + col) * INNER_ + ks*32 + quad*8);
#pragma unroll
        for (int nb = 0; nb < 4; ++nb) {
            bf16x8 bfv = *(const bf16x8*)(arow_base + (size_t)(nb*16 + col) * INNER_ + ks*32 + quad*8);
            acc[nb] = MFMA16(af, bfv, acc[nb]);
        }
    }
    float bias[4];
#pragma unroll
    for (int r = 0; r < 4; ++r) bias[r] = b_out[o0 + quad*4 + r];
    float* dst = out + ((size_t)b * C_ + o0) * N_ + nt*64;
#pragma unroll
    for (int nb = 0; nb < 4; ++nb)
#pragma unroll
        for (int r = 0; r < 4; ++r)
            dst[(size_t)(quad*4 + r) * N_ + nb*16 + col] = acc[nb][r] + bias[r];
}

// ---------------- launch ----------------
extern "C" void kernel_launch(void* const* d_in, const int* in_sizes, int n_in,
                              void* d_out, int out_size, void* d_ws, size_t ws_size,
                              hipStream_t stream) {
    const float* x     = (const float*)d_in[0];
    const float* w_qkv = (const float*)d_in[1];
    const float* w_out = (const float*)d_in[2];
    const float* b_out = (const float*)d_in[3];
    float* out = (float*)d_out;

    char* ws = (char*)d_ws;
    // byte offsets (16B-aligned): xT | Qn | Kn | Vt | AO | wqb | wob
    u16* xT  = (u16*)(ws);
    u16* Qn  = (u16*)(ws + 4718592);
    u16* Kn  = (u16*)(ws + 14155776);
    u16* Vt  = (u16*)(ws + 23592960);
    u16* AO  = (u16*)(ws + 33030144);
    u16* wqb = (u16*)(ws + 42467328);
    u16* wob = (u16*)(ws + 43253760);

    hipLaunchKernelGGL(k_cvt,       dim3(384), dim3(256), 0, stream, w_qkv, wqb, 98304);
    hipLaunchKernelGGL(k_cvt,       dim3(128), dim3(256), 0, stream, w_out, wob, 32768);
    hipLaunchKernelGGL(k_transpose, dim3(N_/64, C_/64, B_), dim3(256), 0, stream, x, xT);
    hipLaunchKernelGGL(k_qkv,       dim3(24, N_/64, B_),    dim3(256), 0, stream, wqb, xT, Qn, Kn, Vt);
    hipLaunchKernelGGL(k_attn,      dim3(N_/64, HEADS_, B_),dim3(256), 0, stream, Qn, Kn, Vt, AO);
    hipLaunchKernelGGL(k_proj,      dim3(C_/64, N_/64, B_), dim3(256), 0, stream, wob, b_out, AO, out);
}